// Round 15
// baseline (36.642 us; speedup 1.0000x reference)
//
#include <hip/hip_runtime.h>

#define MARGIN 0.2f
#define EPSF   1e-16f

constexpr int BSZ  = 512;   // batch
constexpr int DIM  = 1024;  // embedding dim
constexpr int PMAX = 24;    // max positives/anchor (data max ~<=14; R5/R6 verified)
constexpr int NGB  = 256;   // GEMM blocks (16x16 grid of 32x32 tiles)
constexpr int NPB  = 128;   // posval blocks (4 anchors each, 1 wave/anchor)

typedef __attribute__((ext_vector_type(8))) short    bf16x8;
typedef __attribute__((ext_vector_type(4))) unsigned uint4v;
typedef __attribute__((ext_vector_type(4))) float    f32x4;
using ull = unsigned long long;

// 8x f32 -> 8x bf16 via v_cvt_pk_bf16_f32 (RNE). A and B use the same packing;
// dot products are k-permutation invariant, so in-lane order is free.
__device__ __forceinline__ bf16x8 cvt8(float4 a, float4 b) {
    uint4v u;
    asm("v_cvt_pk_bf16_f32 %0, %1, %2" : "=v"(u[0]) : "v"(a.x), "v"(a.y));
    asm("v_cvt_pk_bf16_f32 %0, %1, %2" : "=v"(u[1]) : "v"(a.z), "v"(a.w));
    asm("v_cvt_pk_bf16_f32 %0, %1, %2" : "=v"(u[2]) : "v"(b.x), "v"(b.y));
    asm("v_cvt_pk_bf16_f32 %0, %1, %2" : "=v"(u[3]) : "v"(b.z), "v"(b.w));
    return __builtin_bit_cast(bf16x8, u);
}

// ---------------- Single fused kernel (384 blocks x 256 thr) ----------------
// Blocks [256..384): posval producers. Block pb: anchors pb*4+w, one wave
//   each: ballot-walked positives (ascending p, deterministic), cooperative
//   64-lane f32 dot (R5-proven), agent-scope stores, vmcnt-ack, pctr RMW.
// Blocks [0..256): GEMM 32x32 tile, FULL K (so hinge runs on registers).
//   K split 4 ways across waves (R13 fragment code), 16 KB LDS combine in
//   fixed order, spin on pctr (relaxed agent loads - R12-proven), hinge
//   epilogue vs LDS-staged posvals (R5-proven), then R11/R14's de-contended
//   256-partial finalize protocol. No pw materialization at all.
__global__ void __launch_bounds__(256) fused(const float* __restrict__ I,
                                             const float* __restrict__ S,
                                             const int*   __restrict__ labels,
                                             float* __restrict__ posvals,
                                             int*   __restrict__ npos,
                                             ull*   __restrict__ part,
                                             unsigned* __restrict__ ctrs,  // [0]=pctr [1]=gate
                                             float* __restrict__ out) {
    const int tid  = threadIdx.x;
    const int lane = tid & 63;
    const int w    = tid >> 6;
    const int r    = lane & 15;
    const int hi   = lane >> 4;

    if (blockIdx.x >= NGB) {
        // ---------------- posval producer ----------------
        __shared__ int lab_s[BSZ];
        if (tid < 128) ((int4*)lab_s)[tid] = ((const int4*)labels)[tid];
        __syncthreads();

        const int a  = (blockIdx.x - NGB) * 4 + w;
        const int la = lab_s[a];
        float4 av[4];
#pragma unroll
        for (int j = 0; j < 4; ++j)
            av[j] = *(const float4*)(I + (size_t)a * DIM + j * 256 + lane * 4);

        int idx = 0;
        for (int p0 = 0; p0 < BSZ; p0 += 64) {
            unsigned long long m = __ballot(lab_s[p0 + lane] == la);
            while (m) {                               // ascending p, uniform
                const int p = p0 + __ffsll((long long)m) - 1;
                m &= m - 1;
                if (idx < PMAX) {
                    const float* Sp = S + (size_t)p * DIM;
                    float s = 0.f;
#pragma unroll
                    for (int j = 0; j < 4; ++j) {
                        const float4 b = *(const float4*)(Sp + j * 256 + lane * 4);
                        s += av[j].x * b.x + av[j].y * b.y + av[j].z * b.z + av[j].w * b.w;
                    }
#pragma unroll
                    for (int off = 32; off > 0; off >>= 1) s += __shfl_down(s, off);
                    if (lane == 0)
                        __hip_atomic_store(&posvals[a * PMAX + idx], s,
                                           __ATOMIC_RELAXED, __HIP_MEMORY_SCOPE_AGENT);
                }
                ++idx;
            }
        }
        if (lane == 0)
            __hip_atomic_store(&npos[a], (idx < PMAX) ? idx : PMAX,
                               __ATOMIC_RELAXED, __HIP_MEMORY_SCOPE_AGENT);
        asm volatile("s_waitcnt vmcnt(0)" ::: "memory");   // per-wave store ack
        __syncthreads();
        if (tid == 0)
            __hip_atomic_fetch_add(&ctrs[0], 1u, __ATOMIC_RELAXED,
                                   __HIP_MEMORY_SCOPE_AGENT);
        return;
    }

    // ---------------- GEMM + hinge ----------------
    __shared__ f32x4 lds[4][4][64];            // 16 KB combine buffer
    __shared__ float pv_s[32][PMAX];
    __shared__ int   np_s[32], labr[32], labc[32];
    __shared__ float wsum_s[4];
    __shared__ int   wcnt_s[4];
    __shared__ unsigned is_last;

    const int tile = ((blockIdx.x & 7) << 5) | (blockIdx.x >> 3);  // bijective
    const int tr   = (tile >> 4) * 32;
    const int tc   = (tile & 15) * 32;

    if (tid < 32)            labr[tid]      = labels[tr + tid];
    else if (tid < 64)       labc[tid - 32] = labels[tc + tid - 32];

    const float* A0 = I + (size_t)(tr + r) * DIM + w * 256 + hi * 8;
    const float* A1 = A0 + (size_t)16 * DIM;
    const float* B0 = S + (size_t)(tc + r) * DIM + w * 256 + hi * 8;
    const float* B1 = B0 + (size_t)16 * DIM;

    f32x4 a00 = {0.f, 0.f, 0.f, 0.f};
    f32x4 a01 = {0.f, 0.f, 0.f, 0.f};
    f32x4 a10 = {0.f, 0.f, 0.f, 0.f};
    f32x4 a11 = {0.f, 0.f, 0.f, 0.f};
#pragma unroll
    for (int t = 0; t < 8; ++t) {              // K quarter = 8 k-steps of 32
        const bf16x8 fa0 = cvt8(*(const float4*)(A0 + t * 32), *(const float4*)(A0 + t * 32 + 4));
        const bf16x8 fa1 = cvt8(*(const float4*)(A1 + t * 32), *(const float4*)(A1 + t * 32 + 4));
        const bf16x8 fb0 = cvt8(*(const float4*)(B0 + t * 32), *(const float4*)(B0 + t * 32 + 4));
        const bf16x8 fb1 = cvt8(*(const float4*)(B1 + t * 32), *(const float4*)(B1 + t * 32 + 4));
        a00 = __builtin_amdgcn_mfma_f32_16x16x32_bf16(fa0, fb0, a00, 0, 0, 0);
        a01 = __builtin_amdgcn_mfma_f32_16x16x32_bf16(fa0, fb1, a01, 0, 0, 0);
        a10 = __builtin_amdgcn_mfma_f32_16x16x32_bf16(fa1, fb0, a10, 0, 0, 0);
        a11 = __builtin_amdgcn_mfma_f32_16x16x32_bf16(fa1, fb1, a11, 0, 0, 0);
    }
    lds[w][0][lane] = a00;
    lds[w][1][lane] = a01;
    lds[w][2][lane] = a10;
    lds[w][3][lane] = a11;

    // spin until posvals ready (relaxed agent loads; one acquire at the end)
    if (tid == 0) {
        while (__hip_atomic_load(&ctrs[0], __ATOMIC_RELAXED,
                                 __HIP_MEMORY_SCOPE_AGENT) < (unsigned)NPB)
            __builtin_amdgcn_s_sleep(8);
        (void)__hip_atomic_load(&ctrs[0], __ATOMIC_ACQUIRE,
                                __HIP_MEMORY_SCOPE_AGENT);
    }
    __syncthreads();                            // frags staged + posvals ready

    // stage this tile's 32 row-anchor posvals (agent loads: replay-safe)
    if (tid < 32)
        np_s[tid] = __hip_atomic_load(&npos[tr + tid], __ATOMIC_RELAXED,
                                      __HIP_MEMORY_SCOPE_AGENT);
    for (int i = tid; i < 32 * PMAX; i += 256)
        pv_s[i / PMAX][i % PMAX] =
            __hip_atomic_load(&posvals[(tr + i / PMAX) * PMAX + (i % PMAX)],
                              __ATOMIC_RELAXED, __HIP_MEMORY_SCOPE_AGENT);
    __syncthreads();

    // combine frag w in fixed order (w0+w1+w2+w3), then hinge on registers
    f32x4 c = lds[0][w][lane];
    c += lds[1][w][lane];
    c += lds[2][w][lane];
    c += lds[3][w][lane];
    const int g  = w >> 1, h = w & 1;
    const int ln = labc[h * 16 + r];
    float sum = 0.f;
    int   cnt = 0;
#pragma unroll
    for (int e = 0; e < 4; ++e) {
        const int rowL = g * 16 + hi * 4 + e;   // local anchor 0..31
        if (ln != labr[rowL]) {                 // column is a negative
            const int np = np_s[rowL];
            for (int i = 0; i < np; ++i) {
                const float v = pv_s[rowL][i] - c[e] + MARGIN;
                sum += fmaxf(v, 0.f);
                cnt += (v > EPSF) ? 1 : 0;
            }
        }
    }

#pragma unroll
    for (int off = 32; off > 0; off >>= 1) {
        sum += __shfl_down(sum, off);
        cnt += __shfl_down(cnt, off);
    }
    if (lane == 0) { wsum_s[w] = sum; wcnt_s[w] = cnt; }
    __syncthreads();

    if (tid == 0) {
        const float s  = wsum_s[0] + wsum_s[1] + wsum_s[2] + wsum_s[3];
        const float cc = (float)(wcnt_s[0] + wcnt_s[1] + wcnt_s[2] + wcnt_s[3]);
        const float2 pk = make_float2(s, cc);
        __hip_atomic_store(&part[blockIdx.x], __builtin_bit_cast(ull, pk),
                           __ATOMIC_RELAXED, __HIP_MEMORY_SCOPE_AGENT);
        asm volatile("s_waitcnt vmcnt(0)" ::: "memory");
        const unsigned old = __hip_atomic_fetch_add(&ctrs[1], 1u, __ATOMIC_RELAXED,
                                                    __HIP_MEMORY_SCOPE_AGENT);
        is_last = (old == (unsigned)(NGB - 1)) ? 1u : 0u;
    }
    __syncthreads();

    if (is_last) {                              // last GEMM block finalizes
        const ull v = __hip_atomic_load(&part[tid], __ATOMIC_RELAXED,
                                        __HIP_MEMORY_SCOPE_AGENT);
        const float2 f = __builtin_bit_cast(float2, v);
        float s = f.x, cc = f.y;
#pragma unroll
        for (int off = 32; off > 0; off >>= 1) {
            s  += __shfl_down(s, off);
            cc += __shfl_down(cc, off);
        }
        if (lane == 0) { wsum_s[w] = s; wcnt_s[w] = (int)cc; }
        __syncthreads();
        if (tid == 0) {
            const float S_ = wsum_s[0] + wsum_s[1] + wsum_s[2] + wsum_s[3];
            const float C_ = (float)(wcnt_s[0] + wcnt_s[1] + wcnt_s[2] + wcnt_s[3]);
            out[0] = S_ / (C_ + EPSF);
        }
    }
}

extern "C" void kernel_launch(void* const* d_in, const int* in_sizes, int n_in,
                              void* d_out, int out_size, void* d_ws, size_t ws_size,
                              hipStream_t stream) {
    const int*   labels = (const int*)d_in[0];
    const float* img    = (const float*)d_in[1];
    const float* sen    = (const float*)d_in[2];
    float* out = (float*)d_out;

    // ws: ctrs (memset 8 B), posvals 48 KB, npos 2 KB, part 2 KB
    unsigned* ctrs    = (unsigned*)d_ws;
    float*    posvals = (float*)((char*)d_ws + 1024);
    int*      npos    = (int*)((char*)d_ws + 1024 + BSZ * PMAX * 4);
    ull*      part    = (ull*)((char*)d_ws + 1024 + BSZ * PMAX * 4 + 2048);

    hipMemsetAsync(d_ws, 0, 8, stream);
    fused<<<NGB + NPB, 256, 0, stream>>>(img, sen, labels, posvals, npos, part, ctrs, out);
}

// Round 16
// 21.310 us; speedup vs baseline: 1.7195x; 1.7195x over previous
//
#include <hip/hip_runtime.h>

#define MARGIN 0.2f
#define EPSF   1e-16f

constexpr int BSZ  = 512;   // batch
constexpr int DIM  = 1024;  // embedding dim
constexpr int NKP  = 8;     // K planes
constexpr int RBLK = 256;   // reduce blocks (2 anchors each)
constexpr int PWSZ = BSZ * BSZ;   // one pw partial plane (f32)

typedef __attribute__((ext_vector_type(8))) short    bf16x8;
typedef __attribute__((ext_vector_type(4))) unsigned uint4v;
typedef __attribute__((ext_vector_type(4))) float    f32x4;
using ull = unsigned long long;

// 8x f32 -> 8x bf16 via v_cvt_pk_bf16_f32 (RNE). A and B use the same packing;
// dot products are k-permutation invariant, so in-lane order is free.
__device__ __forceinline__ bf16x8 cvt8(float4 a, float4 b) {
    uint4v u;
    asm("v_cvt_pk_bf16_f32 %0, %1, %2" : "=v"(u[0]) : "v"(a.x), "v"(a.y));
    asm("v_cvt_pk_bf16_f32 %0, %1, %2" : "=v"(u[1]) : "v"(a.z), "v"(a.w));
    asm("v_cvt_pk_bf16_f32 %0, %1, %2" : "=v"(u[2]) : "v"(b.x), "v"(b.y));
    asm("v_cvt_pk_bf16_f32 %0, %1, %2" : "=v"(u[3]) : "v"(b.z), "v"(b.w));
    return __builtin_bit_cast(bf16x8, u);
}

// ---------------- Node 1: MFMA GEMM, 64x64 tile, K-eighth per block ---------
// 512 blocks x 4 waves = 64 tiles x 8 K-eighths -> 2 blocks/CU (2 waves/SIMD).
// Block (tile, kp): 4x4 16x16 fragments over k in [kp*128, +128); wave w
// covers k-sub [kp*128 + w*32, +32) (1 k-step) of all 128 rows -> 64 KB/block,
// zero intra-block redundancy, 32 MB aggregate reads. Cross-wave combine via
// LDS (fixed order w0+w1+w2+w3); each wave stores 4 fragments to plane[kp]
// (each dword written exactly once -> no init/atomics). XCD swizzle:
// xcd = bid&7 owns tiles [8*xcd, +8) = one 64-row A-strip + B (L2-resident).
// Block 0 zeroes ctr for node 2. mfma layout: A/B row|col = lane&15,
// k = (lane>>4)*8 + j; C/D: col = lane&15, row = (lane>>4)*4 + q.
__global__ void __launch_bounds__(256) mfma_gemm(const float* __restrict__ I,
                                                 const float* __restrict__ S,
                                                 float* __restrict__ pwp,
                                                 unsigned* __restrict__ ctr) {
    __shared__ f32x4 lds[4][16][64];                 // 64 KB

    const int tid  = threadIdx.x;
    const int lane = tid & 63;
    const int w    = tid >> 6;                       // k-sub within eighth
    const int idx  = ((blockIdx.x & 7) << 6) | (blockIdx.x >> 3);  // bijective
    const int tile = idx >> 3;                       // 0..63 (8x8 tile grid)
    const int kp   = idx & 7;                        // K eighth
    const int tr   = (tile >> 3) * 64;               // anchor base
    const int tc   = (tile & 7) * 64;                // negative base
    const int r    = lane & 15;
    const int hi   = lane >> 4;
    const int kbase = kp * 128 + w * 32 + hi * 8;

    if (blockIdx.x == 0 && tid == 0) *ctr = 0u;

    f32x4 acc[4][4];
#pragma unroll
    for (int g = 0; g < 4; ++g)
#pragma unroll
        for (int h = 0; h < 4; ++h)
            acc[g][h] = (f32x4){0.f, 0.f, 0.f, 0.f};

    bf16x8 fa[4], fb[4];
#pragma unroll
    for (int g = 0; g < 4; ++g) {
        const float* Ap = I + (size_t)(tr + g * 16 + r) * DIM + kbase;
        fa[g] = cvt8(*(const float4*)Ap, *(const float4*)(Ap + 4));
    }
#pragma unroll
    for (int h = 0; h < 4; ++h) {
        const float* Bp = S + (size_t)(tc + h * 16 + r) * DIM + kbase;
        fb[h] = cvt8(*(const float4*)Bp, *(const float4*)(Bp + 4));
    }
#pragma unroll
    for (int g = 0; g < 4; ++g)
#pragma unroll
        for (int h = 0; h < 4; ++h)
            acc[g][h] = __builtin_amdgcn_mfma_f32_16x16x32_bf16(
                            fa[g], fb[h], acc[g][h], 0, 0, 0);

    // cross-wave combine (fixed order) distributed over waves
#pragma unroll
    for (int g = 0; g < 4; ++g)
#pragma unroll
        for (int h = 0; h < 4; ++h)
            lds[w][g * 4 + h][lane] = acc[g][h];
    __syncthreads();

    float* const plane = pwp + (size_t)kp * PWSZ;
#pragma unroll
    for (int i = 0; i < 4; ++i) {                    // wave w -> frags w*4+i
        const int f = w * 4 + i;
        const int g = f >> 2, h = f & 3;
        f32x4 v = lds[0][f][lane];
        v += lds[1][f][lane];
        v += lds[2][f][lane];
        v += lds[3][f][lane];
        const int orow = tr + g * 16 + hi * 4;
        const int ocol = tc + h * 16 + r;
#pragma unroll
        for (int e = 0; e < 4; ++e)
            plane[(orow + e) * BSZ + ocol] = v[e];
    }
}

// ---------------- Node 2: 2-anchor triplet reduce + de-contended finalize ---
// 256 blocks x 256 thr; anchor = a0 + (w>>1), negatives window
// [(w&1)*256, +256) per wave. Staging: 1 float4/thread/plane, 8 planes summed
// in fixed order. R11 protocol at 256 partials; last block finalizes.
__global__ void __launch_bounds__(256) triplet_reduce(const float* __restrict__ pwp,
                                                      const int*   __restrict__ labels,
                                                      ull* __restrict__ part,
                                                      unsigned* __restrict__ ctr,
                                                      float* __restrict__ out) {
    __shared__ int   lab[BSZ];
    __shared__ float rows[2][BSZ];
    __shared__ float wsum_s[4];
    __shared__ int   wcnt_s[4];
    __shared__ unsigned is_last;

    const int tid  = threadIdx.x;
    const int lane = tid & 63;
    const int w    = tid >> 6;
    const int a0   = blockIdx.x * 2;

    if (tid < 128) ((int4*)lab)[tid] = ((const int4*)labels)[tid];
    {
        // 2 rows x 128 float4 = 256 float4 -> 1 per thread, 8 planes summed
        const float4* p0 = (const float4*)(pwp + (size_t)a0 * BSZ);
        float4 v = p0[tid];
#pragma unroll
        for (int p = 1; p < NKP; ++p) {
            const float4 u = ((const float4*)(pwp + (size_t)p * PWSZ + (size_t)a0 * BSZ))[tid];
            v.x += u.x; v.y += u.y; v.z += u.z; v.w += u.w;
        }
        ((float4*)rows)[tid] = v;
    }
    __syncthreads();

    const int aw = w >> 1;                            // anchor 0/1
    const int nb = (w & 1) * 256;                     // negative window base
    const int la = lab[a0 + aw];

    float vn[4];
    bool  ng[4];
#pragma unroll
    for (int j = 0; j < 4; ++j) {
        const int n = nb + j * 64 + lane;
        vn[j] = rows[aw][n];
        ng[j] = (lab[n] != la);
    }

    float sum = 0.f;
    int   cnt = 0;
    for (int p0 = 0; p0 < BSZ; p0 += 64) {
        unsigned long long m = __ballot(lab[p0 + lane] == la);
        while (m) {                                   // ascending p, uniform
            const int p = p0 + __ffsll((long long)m) - 1;
            m &= m - 1;
            const float pv = rows[aw][p] + MARGIN;    // LDS broadcast
#pragma unroll
            for (int j = 0; j < 4; ++j) {
                const float v = pv - vn[j];
                sum += ng[j] ? fmaxf(v, 0.f) : 0.f;
                cnt += (ng[j] && v > EPSF) ? 1 : 0;
            }
        }
    }

#pragma unroll
    for (int off = 32; off > 0; off >>= 1) {
        sum += __shfl_down(sum, off);
        cnt += __shfl_down(cnt, off);
    }
    if (lane == 0) { wsum_s[w] = sum; wcnt_s[w] = cnt; }
    __syncthreads();

    if (tid == 0) {
        const float s = wsum_s[0] + wsum_s[1] + wsum_s[2] + wsum_s[3];
        const float c = (float)(wcnt_s[0] + wcnt_s[1] + wcnt_s[2] + wcnt_s[3]);
        const float2 pk2 = make_float2(s, c);
        __hip_atomic_store(&part[blockIdx.x], __builtin_bit_cast(ull, pk2),
                           __ATOMIC_RELAXED, __HIP_MEMORY_SCOPE_AGENT);
        asm volatile("s_waitcnt vmcnt(0)" ::: "memory");   // store performed
        const unsigned old = __hip_atomic_fetch_add(ctr, 1u, __ATOMIC_RELAXED,
                                                    __HIP_MEMORY_SCOPE_AGENT);
        is_last = (old == (unsigned)(RBLK - 1)) ? 1u : 0u;
    }
    __syncthreads();

    if (is_last) {                                    // 256th block: finalize
        const ull v = __hip_atomic_load(&part[tid], __ATOMIC_RELAXED,
                                        __HIP_MEMORY_SCOPE_AGENT);
        const float2 f = __builtin_bit_cast(float2, v);
        float s = f.x, c = f.y;
#pragma unroll
        for (int off = 32; off > 0; off >>= 1) {
            s += __shfl_down(s, off);
            c += __shfl_down(c, off);
        }
        if (lane == 0) { wsum_s[w] = s; wcnt_s[w] = (int)c; }
        __syncthreads();
        if (tid == 0) {
            const float S_ = wsum_s[0] + wsum_s[1] + wsum_s[2] + wsum_s[3];
            const float C_ = (float)(wcnt_s[0] + wcnt_s[1] + wcnt_s[2] + wcnt_s[3]);
            out[0] = S_ / (C_ + EPSF);
        }
    }
}

extern "C" void kernel_launch(void* const* d_in, const int* in_sizes, int n_in,
                              void* d_out, int out_size, void* d_ws, size_t ws_size,
                              hipStream_t stream) {
    const int*   labels = (const int*)d_in[0];
    const float* img    = (const float*)d_in[1];
    const float* sen    = (const float*)d_in[2];
    float* out = (float*)d_out;

    // workspace: ctr (zeroed by node 1), pw planes 8 x 1 MB, partials (2 KB)
    unsigned* ctr  = (unsigned*)d_ws;
    float*    pwp  = (float*)((char*)d_ws + 256);
    ull*      part = (ull*)((char*)d_ws + 256 + (size_t)NKP * PWSZ * 4);

    mfma_gemm<<<512, 256, 0, stream>>>(img, sen, pwp, ctr);
    triplet_reduce<<<RBLK, 256, 0, stream>>>(pwp, labels, part, ctr, out);
}

// Round 17
// 19.013 us; speedup vs baseline: 1.9273x; 1.1208x over previous
//
#include <hip/hip_runtime.h>

#define MARGIN 0.2f
#define EPSF   1e-16f

constexpr int BSZ  = 512;   // batch
constexpr int DIM  = 1024;  // embedding dim
constexpr int NKP  = 4;     // K planes
constexpr int RBLK = 256;   // reduce blocks (2 anchors each)
constexpr int PWSZ = BSZ * BSZ;   // one pw partial plane (f32)

typedef __attribute__((ext_vector_type(8))) short    bf16x8;
typedef __attribute__((ext_vector_type(4))) unsigned uint4v;
typedef __attribute__((ext_vector_type(4))) float    f32x4;
using ull = unsigned long long;

// 8x f32 -> 8x bf16 via v_cvt_pk_bf16_f32 (RNE). A and B use the same packing;
// dot products are k-permutation invariant, so in-lane order is free.
__device__ __forceinline__ bf16x8 cvt8(float4 a, float4 b) {
    uint4v u;
    asm("v_cvt_pk_bf16_f32 %0, %1, %2" : "=v"(u[0]) : "v"(a.x), "v"(a.y));
    asm("v_cvt_pk_bf16_f32 %0, %1, %2" : "=v"(u[1]) : "v"(a.z), "v"(a.w));
    asm("v_cvt_pk_bf16_f32 %0, %1, %2" : "=v"(u[2]) : "v"(b.x), "v"(b.y));
    asm("v_cvt_pk_bf16_f32 %0, %1, %2" : "=v"(u[3]) : "v"(b.z), "v"(b.w));
    return __builtin_bit_cast(bf16x8, u);
}

// ---------------- Node 1: MFMA GEMM (R14 structure, byte-identical) ---------
// 256 blocks x 4 waves = 64 tiles x 4 K-quarters. Block (tile, kq): 4x4 16x16
// fragments over k in [kq*256, +256); wave w covers k-sub [w*64, +64)
// (2 k-steps) of all 128 rows -> 128 KB/block, zero intra-block redundancy.
// Cross-wave combine via LDS (fixed order w0+w1+w2+w3); each wave stores 4
// fragments to plane[kq] (each dword written exactly once -> no init/atomics).
// XCD swizzle: xcd = bid&7 owns 8 consecutive tiles. Block 0 zeroes ctr.
// mfma: A/B row|col = lane&15, k = (lane>>4)*8 + j; C/D col = lane&15,
// row = (lane>>4)*4 + q.
__global__ void __launch_bounds__(256) mfma_gemm(const float* __restrict__ I,
                                                 const float* __restrict__ S,
                                                 float* __restrict__ pwp,
                                                 unsigned* __restrict__ ctr) {
    __shared__ f32x4 lds[4][16][64];                 // 64 KB

    const int tid  = threadIdx.x;
    const int lane = tid & 63;
    const int w    = tid >> 6;                       // K-sub 0..3 within quarter
    const int tid8 = ((blockIdx.x & 7) << 5) | (blockIdx.x >> 3);  // bijective
    const int tile = tid8 >> 2;                      // 0..63 (8x8 tile grid)
    const int kq   = tid8 & 3;                       // K quarter
    const int tr   = (tile >> 3) * 64;               // anchor base
    const int tc   = (tile & 7) * 64;                // negative base
    const int r    = lane & 15;
    const int hi   = lane >> 4;
    const int kbase = kq * 256 + w * 64 + hi * 8;

    if (blockIdx.x == 0 && tid == 0) *ctr = 0u;

    const float* Ap[4];
    const float* Bp[4];
#pragma unroll
    for (int g = 0; g < 4; ++g) {
        Ap[g] = I + (size_t)(tr + g * 16 + r) * DIM + kbase;
        Bp[g] = S + (size_t)(tc + g * 16 + r) * DIM + kbase;
    }

    f32x4 acc[4][4];
#pragma unroll
    for (int g = 0; g < 4; ++g)
#pragma unroll
        for (int h = 0; h < 4; ++h)
            acc[g][h] = (f32x4){0.f, 0.f, 0.f, 0.f};

#pragma unroll
    for (int t = 0; t < 2; ++t) {                    // 2 k-steps of 32
        bf16x8 fa[4], fb[4];
#pragma unroll
        for (int g = 0; g < 4; ++g)
            fa[g] = cvt8(*(const float4*)(Ap[g] + t * 32),
                         *(const float4*)(Ap[g] + t * 32 + 4));
#pragma unroll
        for (int h = 0; h < 4; ++h)
            fb[h] = cvt8(*(const float4*)(Bp[h] + t * 32),
                         *(const float4*)(Bp[h] + t * 32 + 4));
#pragma unroll
        for (int g = 0; g < 4; ++g)
#pragma unroll
            for (int h = 0; h < 4; ++h)
                acc[g][h] = __builtin_amdgcn_mfma_f32_16x16x32_bf16(
                                fa[g], fb[h], acc[g][h], 0, 0, 0);
    }

    // cross-wave combine (fixed order) distributed over waves
#pragma unroll
    for (int g = 0; g < 4; ++g)
#pragma unroll
        for (int h = 0; h < 4; ++h)
            lds[w][g * 4 + h][lane] = acc[g][h];
    __syncthreads();

    float* const plane = pwp + (size_t)kq * PWSZ;
#pragma unroll
    for (int i = 0; i < 4; ++i) {                    // wave w -> frags w*4+i
        const int f = w * 4 + i;
        const int g = f >> 2, h = f & 3;
        f32x4 v = lds[0][f][lane];
        v += lds[1][f][lane];
        v += lds[2][f][lane];
        v += lds[3][f][lane];
        const int orow = tr + g * 16 + hi * 4;
        const int ocol = tc + h * 16 + r;
#pragma unroll
        for (int e = 0; e < 4; ++e)
            plane[(orow + e) * BSZ + ocol] = v[e];
    }
}

// ---------------- Node 2: 2-anchor triplet reduce + de-contended finalize ---
// 256 blocks x 256 thr; anchor = a0 + (w>>1), negatives window
// [(w&1)*256, +256) per wave. Staging: 1 float4/thread/plane, 4 planes summed
// in fixed order (16 KB/block). R11 protocol at 256 partials; last block
// loads exactly 1 partial/thread and finalizes.
__global__ void __launch_bounds__(256) triplet_reduce(const float* __restrict__ pwp,
                                                      const int*   __restrict__ labels,
                                                      ull* __restrict__ part,
                                                      unsigned* __restrict__ ctr,
                                                      float* __restrict__ out) {
    __shared__ int   lab[BSZ];
    __shared__ float rows[2][BSZ];
    __shared__ float wsum_s[4];
    __shared__ int   wcnt_s[4];
    __shared__ unsigned is_last;

    const int tid  = threadIdx.x;
    const int lane = tid & 63;
    const int w    = tid >> 6;
    const int a0   = blockIdx.x * 2;

    if (tid < 128) ((int4*)lab)[tid] = ((const int4*)labels)[tid];
    {
        // 2 rows x 128 float4 = 256 float4 -> 1 per thread, 4 planes summed
        float4 v = ((const float4*)(pwp + (size_t)a0 * BSZ))[tid];
#pragma unroll
        for (int p = 1; p < NKP; ++p) {
            const float4 u = ((const float4*)(pwp + (size_t)p * PWSZ + (size_t)a0 * BSZ))[tid];
            v.x += u.x; v.y += u.y; v.z += u.z; v.w += u.w;
        }
        ((float4*)rows)[tid] = v;
    }
    __syncthreads();

    const int aw = w >> 1;                            // anchor 0/1
    const int nb = (w & 1) * 256;                     // negative window base
    const int la = lab[a0 + aw];

    float vn[4];
    bool  ng[4];
#pragma unroll
    for (int j = 0; j < 4; ++j) {
        const int n = nb + j * 64 + lane;
        vn[j] = rows[aw][n];
        ng[j] = (lab[n] != la);
    }

    float sum = 0.f;
    int   cnt = 0;
    for (int p0 = 0; p0 < BSZ; p0 += 64) {
        unsigned long long m = __ballot(lab[p0 + lane] == la);
        while (m) {                                   // ascending p, uniform
            const int p = p0 + __ffsll((long long)m) - 1;
            m &= m - 1;
            const float pv = rows[aw][p] + MARGIN;    // LDS broadcast
#pragma unroll
            for (int j = 0; j < 4; ++j) {
                const float v = pv - vn[j];
                sum += ng[j] ? fmaxf(v, 0.f) : 0.f;
                cnt += (ng[j] && v > EPSF) ? 1 : 0;
            }
        }
    }

#pragma unroll
    for (int off = 32; off > 0; off >>= 1) {
        sum += __shfl_down(sum, off);
        cnt += __shfl_down(cnt, off);
    }
    if (lane == 0) { wsum_s[w] = sum; wcnt_s[w] = cnt; }
    __syncthreads();

    if (tid == 0) {
        const float s = wsum_s[0] + wsum_s[1] + wsum_s[2] + wsum_s[3];
        const float c = (float)(wcnt_s[0] + wcnt_s[1] + wcnt_s[2] + wcnt_s[3]);
        const float2 pk2 = make_float2(s, c);
        __hip_atomic_store(&part[blockIdx.x], __builtin_bit_cast(ull, pk2),
                           __ATOMIC_RELAXED, __HIP_MEMORY_SCOPE_AGENT);
        asm volatile("s_waitcnt vmcnt(0)" ::: "memory");   // store performed
        const unsigned old = __hip_atomic_fetch_add(ctr, 1u, __ATOMIC_RELAXED,
                                                    __HIP_MEMORY_SCOPE_AGENT);
        is_last = (old == (unsigned)(RBLK - 1)) ? 1u : 0u;
    }
    __syncthreads();

    if (is_last) {                                    // 256th block: finalize
        const ull v = __hip_atomic_load(&part[tid], __ATOMIC_RELAXED,
                                        __HIP_MEMORY_SCOPE_AGENT);
        const float2 f = __builtin_bit_cast(float2, v);
        float s = f.x, c = f.y;
#pragma unroll
        for (int off = 32; off > 0; off >>= 1) {
            s += __shfl_down(s, off);
            c += __shfl_down(c, off);
        }
        if (lane == 0) { wsum_s[w] = s; wcnt_s[w] = (int)c; }
        __syncthreads();
        if (tid == 0) {
            const float S_ = wsum_s[0] + wsum_s[1] + wsum_s[2] + wsum_s[3];
            const float C_ = (float)(wcnt_s[0] + wcnt_s[1] + wcnt_s[2] + wcnt_s[3]);
            out[0] = S_ / (C_ + EPSF);
        }
    }
}

extern "C" void kernel_launch(void* const* d_in, const int* in_sizes, int n_in,
                              void* d_out, int out_size, void* d_ws, size_t ws_size,
                              hipStream_t stream) {
    const int*   labels = (const int*)d_in[0];
    const float* img    = (const float*)d_in[1];
    const float* sen    = (const float*)d_in[2];
    float* out = (float*)d_out;

    // workspace: ctr (zeroed by node 1), pw planes 4 x 1 MB, partials (2 KB)
    unsigned* ctr  = (unsigned*)d_ws;
    float*    pwp  = (float*)((char*)d_ws + 256);
    ull*      part = (ull*)((char*)d_ws + 256 + (size_t)NKP * PWSZ * 4);

    mfma_gemm<<<256, 256, 0, stream>>>(img, sen, pwp, ctr);
    triplet_reduce<<<RBLK, 256, 0, stream>>>(pwp, labels, part, ctr, out);
}

// Round 18
// 17.932 us; speedup vs baseline: 2.0434x; 1.0603x over previous
//
#include <hip/hip_runtime.h>

#define MARGIN 0.2f
#define EPSF   1e-16f

constexpr int BSZ  = 512;   // batch
constexpr int DIM  = 1024;  // embedding dim
constexpr int RBLK = 128;   // reduce blocks (4 anchors each)
constexpr int PWSZ = BSZ * BSZ;   // one pw partial plane (f32)

typedef __attribute__((ext_vector_type(8))) short    bf16x8;
typedef __attribute__((ext_vector_type(4))) unsigned uint4v;
typedef __attribute__((ext_vector_type(4))) float    f32x4;
using ull = unsigned long long;

// 8x f32 -> 8x bf16 via v_cvt_pk_bf16_f32 (RNE). A and B use the same packing;
// dot products are k-permutation invariant, so in-lane order is free.
__device__ __forceinline__ bf16x8 cvt8(float4 a, float4 b) {
    uint4v u;
    asm("v_cvt_pk_bf16_f32 %0, %1, %2" : "=v"(u[0]) : "v"(a.x), "v"(a.y));
    asm("v_cvt_pk_bf16_f32 %0, %1, %2" : "=v"(u[1]) : "v"(a.z), "v"(a.w));
    asm("v_cvt_pk_bf16_f32 %0, %1, %2" : "=v"(u[2]) : "v"(b.x), "v"(b.y));
    asm("v_cvt_pk_bf16_f32 %0, %1, %2" : "=v"(u[3]) : "v"(b.z), "v"(b.w));
    return __builtin_bit_cast(bf16x8, u);
}

// ---------------- Node 1: MFMA GEMM, 64x64 tile, K-quarter per block --------
// (R14 structure, measured best.) 256 blocks x 4 waves = 64 tiles x 4
// K-quarters. Block (tile, kq): 4x4 16x16 fragments over k in [kq*256, +256);
// wave w covers k-sub [w*64, +64) (2 k-steps) of all 128 rows -> 128 KB/block,
// zero intra-block redundancy, 32 MB aggregate L2 reads. Cross-wave combine
// via LDS (fixed order w0+w1+w2+w3); each wave stores 4 fragments to
// plane[kq] (each dword written exactly once -> no init/atomics). XCD
// swizzle: xcd = bid&7 owns 8 consecutive tiles (one 64-row A-strip + B,
// L2-resident). Block 0 zeroes ctr for node 2's last-block finalize.
// mfma: A/B row|col = lane&15, k = (lane>>4)*8 + j; C/D col = lane&15,
// row = (lane>>4)*4 + q.
__global__ void __launch_bounds__(256) mfma_gemm(const float* __restrict__ I,
                                                 const float* __restrict__ S,
                                                 float* __restrict__ pwp,
                                                 unsigned* __restrict__ ctr) {
    __shared__ f32x4 lds[4][16][64];                 // 64 KB

    const int tid  = threadIdx.x;
    const int lane = tid & 63;
    const int w    = tid >> 6;                       // K-sub 0..3 within quarter
    const int tid8 = ((blockIdx.x & 7) << 5) | (blockIdx.x >> 3);  // bijective
    const int tile = tid8 >> 2;                      // 0..63 (8x8 tile grid)
    const int kq   = tid8 & 3;                       // K quarter
    const int tr   = (tile >> 3) * 64;               // anchor base
    const int tc   = (tile & 7) * 64;                // negative base
    const int r    = lane & 15;
    const int hi   = lane >> 4;
    const int kbase = kq * 256 + w * 64 + hi * 8;

    if (blockIdx.x == 0 && tid == 0) *ctr = 0u;

    const float* Ap[4];
    const float* Bp[4];
#pragma unroll
    for (int g = 0; g < 4; ++g) {
        Ap[g] = I + (size_t)(tr + g * 16 + r) * DIM + kbase;
        Bp[g] = S + (size_t)(tc + g * 16 + r) * DIM + kbase;
    }

    f32x4 acc[4][4];
#pragma unroll
    for (int g = 0; g < 4; ++g)
#pragma unroll
        for (int h = 0; h < 4; ++h)
            acc[g][h] = (f32x4){0.f, 0.f, 0.f, 0.f};

#pragma unroll
    for (int t = 0; t < 2; ++t) {                    // 2 k-steps of 32
        bf16x8 fa[4], fb[4];
#pragma unroll
        for (int g = 0; g < 4; ++g)
            fa[g] = cvt8(*(const float4*)(Ap[g] + t * 32),
                         *(const float4*)(Ap[g] + t * 32 + 4));
#pragma unroll
        for (int h = 0; h < 4; ++h)
            fb[h] = cvt8(*(const float4*)(Bp[h] + t * 32),
                         *(const float4*)(Bp[h] + t * 32 + 4));
#pragma unroll
        for (int g = 0; g < 4; ++g)
#pragma unroll
            for (int h = 0; h < 4; ++h)
                acc[g][h] = __builtin_amdgcn_mfma_f32_16x16x32_bf16(
                                fa[g], fb[h], acc[g][h], 0, 0, 0);
    }

    // cross-wave combine (fixed order) distributed over waves
#pragma unroll
    for (int g = 0; g < 4; ++g)
#pragma unroll
        for (int h = 0; h < 4; ++h)
            lds[w][g * 4 + h][lane] = acc[g][h];
    __syncthreads();

    float* const plane = pwp + (size_t)kq * PWSZ;
#pragma unroll
    for (int i = 0; i < 4; ++i) {                    // wave w -> frags w*4+i
        const int f = w * 4 + i;
        const int g = f >> 2, h = f & 3;
        f32x4 v = lds[0][f][lane];
        v += lds[1][f][lane];
        v += lds[2][f][lane];
        v += lds[3][f][lane];
        const int orow = tr + g * 16 + hi * 4;
        const int ocol = tc + h * 16 + r;
#pragma unroll
        for (int e = 0; e < 4; ++e)
            plane[(orow + e) * BSZ + ocol] = v[e];
    }
}

// ---------------- Node 2: 4-anchor triplet reduce + de-contended finalize ---
// (R11/R14 body.) 128 blocks x 256 thr; wave w owns anchor 4*blk+w. Staging
// sums the 4 K-quarter planes in fixed order (2 float4/thread/plane).
// Ballot-walked positives (ascending p, deterministic), register-cached
// negatives. One packed agent-scope atomic store per block + vmcnt-acked
// relaxed ctr RMW; last block (old==127) loads 128 partials and finalizes.
__global__ void __launch_bounds__(256) triplet_reduce(const float* __restrict__ pwp,
                                                      const int*   __restrict__ labels,
                                                      ull* __restrict__ part,
                                                      unsigned* __restrict__ ctr,
                                                      float* __restrict__ out) {
    __shared__ int   lab[BSZ];
    __shared__ float rows[4][BSZ];
    __shared__ float wsum_s[4];
    __shared__ int   wcnt_s[4];
    __shared__ unsigned is_last;

    const int tid  = threadIdx.x;
    const int lane = tid & 63;
    const int w    = tid >> 6;
    const int a0   = blockIdx.x * 4;

    if (tid < 128) ((int4*)lab)[tid] = ((const int4*)labels)[tid];
    {
        const float4* p0 = (const float4*)(pwp + 0 * (size_t)PWSZ + (size_t)a0 * BSZ);
        const float4* p1 = (const float4*)(pwp + 1 * (size_t)PWSZ + (size_t)a0 * BSZ);
        const float4* p2 = (const float4*)(pwp + 2 * (size_t)PWSZ + (size_t)a0 * BSZ);
        const float4* p3 = (const float4*)(pwp + 3 * (size_t)PWSZ + (size_t)a0 * BSZ);
#pragma unroll
        for (int j = 0; j < 2; ++j) {
            const int idx = tid + j * 256;           // 512 float4 = 4 rows
            float4 v = p0[idx];
            const float4 v1 = p1[idx], v2 = p2[idx], v3 = p3[idx];
            v.x += v1.x; v.y += v1.y; v.z += v1.z; v.w += v1.w;
            v.x += v2.x; v.y += v2.y; v.z += v2.z; v.w += v2.w;
            v.x += v3.x; v.y += v3.y; v.z += v3.z; v.w += v3.w;
            ((float4*)rows)[idx] = v;
        }
    }
    __syncthreads();

    const int la = lab[a0 + w];

    float vn[8];
    bool  ng[8];
#pragma unroll
    for (int j = 0; j < 8; ++j) {
        const int n = j * 64 + lane;
        vn[j] = rows[w][n];
        ng[j] = (lab[n] != la);
    }

    float sum = 0.f;
    int   cnt = 0;
    for (int p0 = 0; p0 < BSZ; p0 += 64) {
        unsigned long long m = __ballot(lab[p0 + lane] == la);
        while (m) {                                   // ascending p, uniform
            const int p = p0 + __ffsll((long long)m) - 1;
            m &= m - 1;
            const float pv = rows[w][p] + MARGIN;     // LDS broadcast
#pragma unroll
            for (int j = 0; j < 8; ++j) {
                const float v = pv - vn[j];
                sum += ng[j] ? fmaxf(v, 0.f) : 0.f;
                cnt += (ng[j] && v > EPSF) ? 1 : 0;
            }
        }
    }

#pragma unroll
    for (int off = 32; off > 0; off >>= 1) {
        sum += __shfl_down(sum, off);
        cnt += __shfl_down(cnt, off);
    }
    if (lane == 0) { wsum_s[w] = sum; wcnt_s[w] = cnt; }
    __syncthreads();

    if (tid == 0) {
        const float s = wsum_s[0] + wsum_s[1] + wsum_s[2] + wsum_s[3];
        const float c = (float)(wcnt_s[0] + wcnt_s[1] + wcnt_s[2] + wcnt_s[3]);
        const float2 pk2 = make_float2(s, c);
        __hip_atomic_store(&part[blockIdx.x], __builtin_bit_cast(ull, pk2),
                           __ATOMIC_RELAXED, __HIP_MEMORY_SCOPE_AGENT);
        asm volatile("s_waitcnt vmcnt(0)" ::: "memory");   // store performed
        const unsigned old = __hip_atomic_fetch_add(ctr, 1u, __ATOMIC_RELAXED,
                                                    __HIP_MEMORY_SCOPE_AGENT);
        is_last = (old == (unsigned)(RBLK - 1)) ? 1u : 0u;
    }
    __syncthreads();

    if (is_last) {                                    // 128th block: finalize
        float s = 0.f, c = 0.f;
        if (tid < RBLK) {
            const ull v = __hip_atomic_load(&part[tid], __ATOMIC_RELAXED,
                                            __HIP_MEMORY_SCOPE_AGENT);
            const float2 f = __builtin_bit_cast(float2, v);
            s = f.x;
            c = f.y;
        }
#pragma unroll
        for (int off = 32; off > 0; off >>= 1) {
            s += __shfl_down(s, off);
            c += __shfl_down(c, off);
        }
        if (lane == 0) { wsum_s[w] = s; wcnt_s[w] = (int)c; }
        __syncthreads();
        if (tid == 0) {
            const float S_ = wsum_s[0] + wsum_s[1] + wsum_s[2] + wsum_s[3];
            const float C_ = (float)(wcnt_s[0] + wcnt_s[1] + wcnt_s[2] + wcnt_s[3]);
            out[0] = S_ / (C_ + EPSF);
        }
    }
}

extern "C" void kernel_launch(void* const* d_in, const int* in_sizes, int n_in,
                              void* d_out, int out_size, void* d_ws, size_t ws_size,
                              hipStream_t stream) {
    const int*   labels = (const int*)d_in[0];
    const float* img    = (const float*)d_in[1];
    const float* sen    = (const float*)d_in[2];
    float* out = (float*)d_out;

    // workspace: ctr (zeroed by node 1), pw partial planes 4 x 1 MB,
    // packed partials (1 KB). All fully written every call -> no init needed.
    unsigned* ctr  = (unsigned*)d_ws;
    float*    pwp  = (float*)((char*)d_ws + 256);
    ull*      part = (ull*)((char*)d_ws + 256 + 4 * (size_t)PWSZ * 4);

    mfma_gemm<<<256, 256, 0, stream>>>(img, sen, pwp, ctr);
    triplet_reduce<<<RBLK, 256, 0, stream>>>(pwp, labels, part, ctr, out);
}